// Round 1
// baseline (5597.414 us; speedup 1.0000x reference)
//
#include <hip/hip_runtime.h>
#include <hip/hip_bf16.h>

#define DIM   2048
#define NEXP  32
#define TOPK  8
#define MDIM  768
#define NTOK  4096
#define NPAIR 32768   // NTOK * TOPK
#define BKP   40      // padded LDS stride (bf16 elems) for transposed B tiles

typedef float        f32x4_t  __attribute__((ext_vector_type(4)));
typedef __bf16       bf16x8_t __attribute__((ext_vector_type(8)));
typedef unsigned int u32x4_t  __attribute__((ext_vector_type(4)));

// ---------------- 1. router: logits -> top8 -> renorm weights; also x -> bf16 ----------------
__global__ __launch_bounds__(256) void router_kernel(
    const float* __restrict__ x, const float* __restrict__ gk,
    __bf16* __restrict__ xb, float* __restrict__ topk_w, int* __restrict__ topk_e)
{
  __shared__ float sx[DIM];
  __shared__ float spart[8][NEXP];
  __shared__ float slog[NEXP];
  const int t = blockIdx.x;
  const int tid = threadIdx.x;
  const float* xrow = x + (size_t)t * DIM;

  for (int i = tid; i < DIM / 4; i += 256)
    ((float4*)sx)[i] = ((const float4*)xrow)[i];
  __syncthreads();

  const int e = tid & 31, part = tid >> 5;
  const float* gcol = gk + e;
  float acc = 0.f;
  #pragma unroll 8
  for (int d = part * 256; d < part * 256 + 256; ++d)
    acc += sx[d] * gcol[(size_t)d * NEXP];
  spart[part][e] = acc;
  __syncthreads();

  if (tid < NEXP) {
    float s = 0.f;
    #pragma unroll
    for (int p = 0; p < 8; ++p) s += spart[p][tid];
    slog[tid] = s;
  }
  __syncthreads();

  if (tid == 0) {
    float lg[NEXP];
    #pragma unroll
    for (int i = 0; i < NEXP; ++i) lg[i] = slog[i];
    float sv[TOPK]; int se[TOPK];
    for (int k = 0; k < TOPK; ++k) {          // top-8 by logit (ties -> lowest index, same as lax.top_k)
      float bv = -1e30f; int bi = 0;
      for (int i = 0; i < NEXP; ++i)
        if (lg[i] > bv) { bv = lg[i]; bi = i; }
      sv[k] = bv; se[k] = bi; lg[bi] = -1e30f;
    }
    // softmax over top-8 logits == softmax-all then renorm over top-8
    float sum = 0.f, w[TOPK];
    for (int k = 0; k < TOPK; ++k) { w[k] = __expf(sv[k] - sv[0]); sum += w[k]; }
    const float inv = 1.f / sum;
    for (int k = 0; k < TOPK; ++k) {
      topk_w[t * TOPK + k] = w[k] * inv;
      topk_e[t * TOPK + k] = se[k];
    }
  }

  for (int i = tid; i < DIM; i += 256)
    xb[(size_t)t * DIM + i] = (__bf16)sx[i];
}

// ---------------- 2. scatter: per-expert row lists (counts -> offsets -> scatter) ----------------
__global__ __launch_bounds__(1024) void scatter_kernel(
    const int* __restrict__ topk_e, const float* __restrict__ topk_w,
    int* __restrict__ meta, int* __restrict__ row_token, float* __restrict__ row_w)
{
  __shared__ int scnt[NEXP], scur[NEXP], soff[NEXP + 1];
  const int tid = threadIdx.x;
  if (tid < NEXP) { scnt[tid] = 0; scur[tid] = 0; }
  __syncthreads();
  for (int i = tid; i < NPAIR; i += 1024)
    atomicAdd(&scnt[topk_e[i]], 1);
  __syncthreads();
  if (tid == 0) {
    int s = 0;
    for (int e2 = 0; e2 < NEXP; ++e2) { soff[e2] = s; s += scnt[e2]; }
    soff[NEXP] = s;
  }
  __syncthreads();
  for (int i = tid; i < NPAIR; i += 1024) {
    const int e2 = topk_e[i];
    const int pos = soff[e2] + atomicAdd(&scur[e2], 1);
    row_token[pos] = i >> 3;     // i = t*8 + k
    row_w[pos] = topk_w[i];
  }
  if (tid <= NEXP) meta[64 + tid] = soff[tid];
}

// ---------------- 3. grouped GEMM: gate & up fused, silu(g)*u -> inter (bf16) ----------------
__global__ __launch_bounds__(256) void gemm1_kernel(
    const __bf16* __restrict__ xb,
    const float* __restrict__ gate_w, const float* __restrict__ up_w,
    const int* __restrict__ meta, const int* __restrict__ row_token,
    __bf16* __restrict__ inter)
{
  const int e  = blockIdx.x >> 5;
  const int mt = blockIdx.x & 31;
  const int off0 = meta[64 + e], off1 = meta[64 + e + 1];
  const int rows = off1 - off0;
  if (mt * 128 >= rows) return;
  const int r0 = off0 + mt * 128;
  const int tile_rows = min(128, rows - mt * 128);
  const int n0 = blockIdx.y * 128;   // 6 n-tiles over M=768

  __shared__ __align__(16) __bf16 sA[128 * 32];
  __shared__ __align__(16) __bf16 sBg[128 * BKP];
  __shared__ __align__(16) __bf16 sBu[128 * BKP];
  __shared__ int stok[128];

  const int tid = threadIdx.x;
  if (tid < 128) stok[tid] = row_token[min(r0 + tid, NPAIR - 1)];
  __syncthreads();

  const int wave = tid >> 6, lane = tid & 63;
  const int quad = lane >> 4, l16 = lane & 15;

  // A staging: 2 threads per row, 16 bf16 each
  const int ra = tid >> 1, qa = tid & 1;
  const __bf16* asrc = xb + (size_t)stok[ra] * DIM + qa * 16;
  // B staging: thread -> (k=kb, n=nb..nb+15), transposed into LDS [n][k]
  const int kb = tid >> 3, nb = (tid & 7) * 16;
  const float* gsrc = gate_w + (size_t)e * DIM * MDIM + (size_t)kb * MDIM + n0 + nb;
  const float* usrc = up_w   + (size_t)e * DIM * MDIM + (size_t)kb * MDIM + n0 + nb;

  f32x4_t accg[2][8], accu[2][8];
  const f32x4_t z = {0.f, 0.f, 0.f, 0.f};
  #pragma unroll
  for (int i = 0; i < 2; ++i)
    #pragma unroll
    for (int j = 0; j < 8; ++j) { accg[i][j] = z; accu[i][j] = z; }

  for (int k0 = 0; k0 < DIM; k0 += 32) {
    u32x4_t a0v = *(const u32x4_t*)(asrc + k0);
    u32x4_t a1v = *(const u32x4_t*)(asrc + k0 + 8);
    *(u32x4_t*)(&sA[ra * 32 + qa * 16])     = a0v;
    *(u32x4_t*)(&sA[ra * 32 + qa * 16 + 8]) = a1v;

    const float* g = gsrc + (size_t)k0 * MDIM;
    const float* u = usrc + (size_t)k0 * MDIM;
    #pragma unroll
    for (int j = 0; j < 4; ++j) {
      float4 vg = *(const float4*)(g + j * 4);
      float4 vu = *(const float4*)(u + j * 4);
      const int n = nb + j * 4;
      sBg[(n + 0) * BKP + kb] = (__bf16)vg.x;
      sBg[(n + 1) * BKP + kb] = (__bf16)vg.y;
      sBg[(n + 2) * BKP + kb] = (__bf16)vg.z;
      sBg[(n + 3) * BKP + kb] = (__bf16)vg.w;
      sBu[(n + 0) * BKP + kb] = (__bf16)vu.x;
      sBu[(n + 1) * BKP + kb] = (__bf16)vu.y;
      sBu[(n + 2) * BKP + kb] = (__bf16)vu.z;
      sBu[(n + 3) * BKP + kb] = (__bf16)vu.w;
    }
    __syncthreads();

    bf16x8_t a0 = *(const bf16x8_t*)(&sA[(wave * 32 +      l16) * 32 + quad * 8]);
    bf16x8_t a1 = *(const bf16x8_t*)(&sA[(wave * 32 + 16 + l16) * 32 + quad * 8]);
    #pragma unroll
    for (int in = 0; in < 8; ++in) {
      bf16x8_t bg = *(const bf16x8_t*)(&sBg[(in * 16 + l16) * BKP + quad * 8]);
      bf16x8_t bu = *(const bf16x8_t*)(&sBu[(in * 16 + l16) * BKP + quad * 8]);
      accg[0][in] = __builtin_amdgcn_mfma_f32_16x16x32_bf16(a0, bg, accg[0][in], 0, 0, 0);
      accg[1][in] = __builtin_amdgcn_mfma_f32_16x16x32_bf16(a1, bg, accg[1][in], 0, 0, 0);
      accu[0][in] = __builtin_amdgcn_mfma_f32_16x16x32_bf16(a0, bu, accu[0][in], 0, 0, 0);
      accu[1][in] = __builtin_amdgcn_mfma_f32_16x16x32_bf16(a1, bu, accu[1][in], 0, 0, 0);
    }
    __syncthreads();
  }

  #pragma unroll
  for (int im = 0; im < 2; ++im) {
    #pragma unroll
    for (int rg = 0; rg < 4; ++rg) {
      const int row = wave * 32 + im * 16 + quad * 4 + rg;  // C/D: col=lane&15, row=quad*4+reg
      if (row < tile_rows) {
        __bf16* orow = inter + (size_t)(r0 + row) * MDIM + n0 + l16;
        #pragma unroll
        for (int in = 0; in < 8; ++in) {
          const float gv = accg[im][in][rg];
          const float uv = accu[im][in][rg];
          const float sl = gv / (1.f + __expf(-gv));
          orow[in * 16] = (__bf16)(sl * uv);
        }
      }
    }
  }
}

// ---------------- 4. grouped GEMM: down proj + weighted atomic combine into out ----------------
__global__ __launch_bounds__(256) void gemm2_kernel(
    const __bf16* __restrict__ inter, const float* __restrict__ down_w,
    const int* __restrict__ meta, const int* __restrict__ row_token,
    const float* __restrict__ row_w, float* __restrict__ out)
{
  const int e  = blockIdx.x >> 5;
  const int mt = blockIdx.x & 31;
  const int off0 = meta[64 + e], off1 = meta[64 + e + 1];
  const int rows = off1 - off0;
  if (mt * 128 >= rows) return;
  const int r0 = off0 + mt * 128;
  const int tile_rows = min(128, rows - mt * 128);
  const int n0 = blockIdx.y * 128;   // 16 n-tiles over D=2048

  __shared__ __align__(16) __bf16 sA[128 * 32];
  __shared__ __align__(16) __bf16 sB[128 * BKP];

  const int tid = threadIdx.x;
  const int wave = tid >> 6, lane = tid & 63;
  const int quad = lane >> 4, l16 = lane & 15;

  const int ra = tid >> 1, qa = tid & 1;
  const __bf16* asrc = inter + (size_t)min(r0 + ra, NPAIR - 1) * MDIM + qa * 16;
  const int kb = tid >> 3, nb = (tid & 7) * 16;
  const float* dsrc = down_w + (size_t)e * MDIM * DIM + (size_t)kb * DIM + n0 + nb;

  f32x4_t acc[2][8];
  const f32x4_t z = {0.f, 0.f, 0.f, 0.f};
  #pragma unroll
  for (int i = 0; i < 2; ++i)
    #pragma unroll
    for (int j = 0; j < 8; ++j) acc[i][j] = z;

  for (int k0 = 0; k0 < MDIM; k0 += 32) {
    u32x4_t a0v = *(const u32x4_t*)(asrc + k0);
    u32x4_t a1v = *(const u32x4_t*)(asrc + k0 + 8);
    *(u32x4_t*)(&sA[ra * 32 + qa * 16])     = a0v;
    *(u32x4_t*)(&sA[ra * 32 + qa * 16 + 8]) = a1v;

    const float* dptr = dsrc + (size_t)k0 * DIM;
    #pragma unroll
    for (int j = 0; j < 4; ++j) {
      float4 vd = *(const float4*)(dptr + j * 4);
      const int n = nb + j * 4;
      sB[(n + 0) * BKP + kb] = (__bf16)vd.x;
      sB[(n + 1) * BKP + kb] = (__bf16)vd.y;
      sB[(n + 2) * BKP + kb] = (__bf16)vd.z;
      sB[(n + 3) * BKP + kb] = (__bf16)vd.w;
    }
    __syncthreads();

    bf16x8_t a0 = *(const bf16x8_t*)(&sA[(wave * 32 +      l16) * 32 + quad * 8]);
    bf16x8_t a1 = *(const bf16x8_t*)(&sA[(wave * 32 + 16 + l16) * 32 + quad * 8]);
    #pragma unroll
    for (int in = 0; in < 8; ++in) {
      bf16x8_t bd = *(const bf16x8_t*)(&sB[(in * 16 + l16) * BKP + quad * 8]);
      acc[0][in] = __builtin_amdgcn_mfma_f32_16x16x32_bf16(a0, bd, acc[0][in], 0, 0, 0);
      acc[1][in] = __builtin_amdgcn_mfma_f32_16x16x32_bf16(a1, bd, acc[1][in], 0, 0, 0);
    }
    __syncthreads();
  }

  #pragma unroll
  for (int im = 0; im < 2; ++im) {
    #pragma unroll
    for (int rg = 0; rg < 4; ++rg) {
      const int row = wave * 32 + im * 16 + quad * 4 + rg;
      if (row < tile_rows) {
        const int pos = r0 + row;
        const int tok = row_token[pos];
        const float wt = row_w[pos];
        float* obase = out + (size_t)tok * DIM + n0 + l16;
        #pragma unroll
        for (int in = 0; in < 8; ++in)
          atomicAdd(obase + in * 16, wt * acc[im][in][rg]);
      }
    }
  }
}

extern "C" void kernel_launch(void* const* d_in, const int* in_sizes, int n_in,
                              void* d_out, int out_size, void* d_ws, size_t ws_size,
                              hipStream_t stream) {
  (void)in_sizes; (void)n_in; (void)ws_size;
  const float* x      = (const float*)d_in[0];  // [4,1024,2048]
  const float* gk     = (const float*)d_in[1];  // [2048,32]
  const float* gate_w = (const float*)d_in[2];  // [32,2048,768]
  const float* up_w   = (const float*)d_in[3];  // [32,2048,768]
  const float* down_w = (const float*)d_in[4];  // [32,768,2048]
  float* out = (float*)d_out;

  char* ws = (char*)d_ws;
  size_t o = 0;
  auto alloc = [&](size_t bytes) { size_t cur = o; o = (o + bytes + 255) & ~(size_t)255; return cur; };
  __bf16* xb        = (__bf16*)(ws + alloc((size_t)NTOK * DIM * 2));
  __bf16* inter     = (__bf16*)(ws + alloc((size_t)NPAIR * MDIM * 2));
  int*    row_token = (int*)   (ws + alloc((size_t)NPAIR * 4));
  float*  row_w     = (float*) (ws + alloc((size_t)NPAIR * 4));
  float*  topk_w    = (float*) (ws + alloc((size_t)NPAIR * 4));
  int*    topk_e    = (int*)   (ws + alloc((size_t)NPAIR * 4));
  int*    meta      = (int*)   (ws + alloc(512));

  hipMemsetAsync(d_out, 0, (size_t)out_size * sizeof(float), stream);

  router_kernel<<<NTOK, 256, 0, stream>>>(x, gk, xb, topk_w, topk_e);
  scatter_kernel<<<1, 1024, 0, stream>>>(topk_e, topk_w, meta, row_token, row_w);
  gemm1_kernel<<<dim3(NEXP * 32, MDIM / 128), 256, 0, stream>>>(xb, gate_w, up_w, meta, row_token, inter);
  gemm2_kernel<<<dim3(NEXP * 32, DIM / 128), 256, 0, stream>>>(inter, down_w, meta, row_token, row_w, out);
}

// Round 2
// 1932.272 us; speedup vs baseline: 2.8968x; 2.8968x over previous
//
#include <hip/hip_runtime.h>
#include <hip/hip_bf16.h>

#define DIM   2048
#define NEXP  32
#define TOPK  8
#define MDIM  768
#define NTOK  4096
#define NPAIR 32768

typedef float        f32x4_t  __attribute__((ext_vector_type(4)));
typedef __bf16       bf16x8_t __attribute__((ext_vector_type(8)));
typedef __bf16       bf16x4_t __attribute__((ext_vector_type(4)));

__device__ __forceinline__ void glds16(const void* g, void* l) {
  __builtin_amdgcn_global_load_lds(
      (const __attribute__((address_space(1))) unsigned int*)g,
      (__attribute__((address_space(3))) unsigned int*)l, 16, 0, 0);
}

// ---------------- 0. weight transpose: fp32 [E][K][N] -> bf16 [E][N][K] ----------------
// tile: 128 (k) x 32 (n). LDS [128][36] bf16 (stride 36: 8B-aligned rows, 2-way-max banks).
__global__ __launch_bounds__(256) void wtrans_kernel(
    const float* __restrict__ in, __bf16* __restrict__ out, int K, int N, int ntn)
{
  __shared__ __align__(16) __bf16 sT[128 * 36];
  const int e  = blockIdx.y;
  const int bk = blockIdx.x / ntn;
  const int bn = blockIdx.x % ntn;
  const int k0 = bk * 128, n0 = bn * 32;
  const int t = threadIdx.x;

  const float* src = in + ((size_t)e * K + k0) * N + n0;
  const int kk = t >> 3, nf = (t & 7) * 4;
  #pragma unroll
  for (int kr = 0; kr < 4; ++kr) {
    const int k = kr * 32 + kk;
    float4 v = *(const float4*)(src + (size_t)k * N + nf);
    bf16x4_t b;
    b[0] = (__bf16)v.x; b[1] = (__bf16)v.y; b[2] = (__bf16)v.z; b[3] = (__bf16)v.w;
    *(bf16x4_t*)(&sT[k * 36 + nf]) = b;
  }
  __syncthreads();

  const int n = t & 31, kc = (t >> 5) * 16;
  bf16x8_t o0, o1;
  #pragma unroll
  for (int j = 0; j < 8; ++j) o0[j] = sT[(kc + j) * 36 + n];
  #pragma unroll
  for (int j = 0; j < 8; ++j) o1[j] = sT[(kc + 8 + j) * 36 + n];
  __bf16* dst = out + ((size_t)e * N + n0 + n) * K + k0 + kc;
  *(bf16x8_t*)dst = o0;
  *(bf16x8_t*)(dst + 8) = o1;
}

// ---------------- 1. router ----------------
__global__ __launch_bounds__(256) void router_kernel(
    const float* __restrict__ x, const float* __restrict__ gk,
    __bf16* __restrict__ xb, float* __restrict__ topk_w, int* __restrict__ topk_e)
{
  __shared__ float sx[DIM];
  __shared__ float spart[8][NEXP];
  __shared__ float slog[NEXP];
  const int t = blockIdx.x;
  const int tid = threadIdx.x;
  const float* xrow = x + (size_t)t * DIM;

  for (int i = tid; i < DIM / 4; i += 256)
    ((float4*)sx)[i] = ((const float4*)xrow)[i];
  __syncthreads();

  const int e = tid & 31, part = tid >> 5;
  const float* gcol = gk + e;
  float acc = 0.f;
  #pragma unroll 8
  for (int d = part * 256; d < part * 256 + 256; ++d)
    acc += sx[d] * gcol[(size_t)d * NEXP];
  spart[part][e] = acc;
  __syncthreads();

  if (tid < NEXP) {
    float s = 0.f;
    #pragma unroll
    for (int p = 0; p < 8; ++p) s += spart[p][tid];
    slog[tid] = s;
  }
  __syncthreads();

  if (tid == 0) {
    float lg[NEXP];
    #pragma unroll
    for (int i = 0; i < NEXP; ++i) lg[i] = slog[i];
    float sv[TOPK]; int se[TOPK];
    for (int k = 0; k < TOPK; ++k) {
      float bv = -1e30f; int bi = 0;
      for (int i = 0; i < NEXP; ++i)
        if (lg[i] > bv) { bv = lg[i]; bi = i; }
      sv[k] = bv; se[k] = bi; lg[bi] = -1e30f;
    }
    float sum = 0.f, w[TOPK];
    for (int k = 0; k < TOPK; ++k) { w[k] = __expf(sv[k] - sv[0]); sum += w[k]; }
    const float inv = 1.f / sum;
    for (int k = 0; k < TOPK; ++k) {
      topk_w[t * TOPK + k] = w[k] * inv;
      topk_e[t * TOPK + k] = se[k];
    }
  }

  for (int i = tid; i < DIM; i += 256)
    xb[(size_t)t * DIM + i] = (__bf16)sx[i];
}

// ---------------- 2. scatter ----------------
__global__ __launch_bounds__(1024) void scatter_kernel(
    const int* __restrict__ topk_e, const float* __restrict__ topk_w,
    int* __restrict__ meta, int* __restrict__ row_token, float* __restrict__ row_w)
{
  __shared__ int scnt[NEXP], scur[NEXP], soff[NEXP + 1];
  const int tid = threadIdx.x;
  if (tid < NEXP) { scnt[tid] = 0; scur[tid] = 0; }
  __syncthreads();
  for (int i = tid; i < NPAIR; i += 1024)
    atomicAdd(&scnt[topk_e[i]], 1);
  __syncthreads();
  if (tid == 0) {
    int s = 0;
    for (int e2 = 0; e2 < NEXP; ++e2) { soff[e2] = s; s += scnt[e2]; }
    soff[NEXP] = s;
  }
  __syncthreads();
  for (int i = tid; i < NPAIR; i += 1024) {
    const int e2 = topk_e[i];
    const int pos = soff[e2] + atomicAdd(&scur[e2], 1);
    row_token[pos] = i >> 3;
    row_w[pos] = topk_w[i];
  }
  if (tid <= NEXP) meta[64 + tid] = soff[tid];
}

// ---------------- 3. gemm1: gate+up fused, silu(g)*u -> inter (bf16) ----------------
// 128x128 tile, BK=32, 2x2 waves of 64x64. All staging via global_load_lds(16B).
__global__ __launch_bounds__(256) void gemm1_kernel(
    const __bf16* __restrict__ xb,
    const __bf16* __restrict__ wtg, const __bf16* __restrict__ wtu,
    const int* __restrict__ meta, const int* __restrict__ row_token,
    __bf16* __restrict__ inter)
{
  const int e  = blockIdx.x >> 4;
  const int mt = blockIdx.x & 15;
  const int off0 = meta[64 + e], off1 = meta[64 + e + 1];
  const int rows = off1 - off0;
  if (mt * 128 >= rows) return;
  const int r0 = off0 + mt * 128;
  const int tile_rows = min(128, rows - mt * 128);
  const int n0 = blockIdx.y * 128;

  __shared__ __align__(16) __bf16 sA[128 * 32];
  __shared__ __align__(16) __bf16 sBg[128 * 32];
  __shared__ __align__(16) __bf16 sBu[128 * 32];
  __shared__ int stok[128];

  const int tid = threadIdx.x;
  if (tid < 128) stok[tid] = row_token[min(r0 + tid, NPAIR - 1)];
  __syncthreads();

  const int wave = tid >> 6, lane = tid & 63;
  const int quad = lane >> 4, l16 = lane & 15;
  const int wr = wave >> 1, wc = wave & 1;

  const int slot0 = wave * 128 + lane;
  const int slot1 = slot0 + 64;
  const size_t aof0 = (size_t)stok[slot0 >> 2] * DIM + (slot0 & 3) * 8;
  const size_t aof1 = (size_t)stok[slot1 >> 2] * DIM + (slot1 & 3) * 8;
  const size_t bof0 = ((size_t)e * MDIM + n0 + (slot0 >> 2)) * DIM + (slot0 & 3) * 8;
  const size_t bof1 = ((size_t)e * MDIM + n0 + (slot1 >> 2)) * DIM + (slot1 & 3) * 8;
  __bf16* ldsA0  = &sA [(wave * 128) * 8];      // wave-uniform base; HW adds lane*16B
  __bf16* ldsA1  = &sA [(wave * 128 + 64) * 8];
  __bf16* ldsBg0 = &sBg[(wave * 128) * 8];
  __bf16* ldsBg1 = &sBg[(wave * 128 + 64) * 8];
  __bf16* ldsBu0 = &sBu[(wave * 128) * 8];
  __bf16* ldsBu1 = &sBu[(wave * 128 + 64) * 8];

  f32x4_t accg[4][4], accu[4][4];
  const f32x4_t z = {0.f, 0.f, 0.f, 0.f};
  #pragma unroll
  for (int i = 0; i < 4; ++i)
    #pragma unroll
    for (int j = 0; j < 4; ++j) { accg[i][j] = z; accu[i][j] = z; }

  for (int k0 = 0; k0 < DIM; k0 += 32) {
    glds16(xb  + aof0 + k0, ldsA0);
    glds16(xb  + aof1 + k0, ldsA1);
    glds16(wtg + bof0 + k0, ldsBg0);
    glds16(wtg + bof1 + k0, ldsBg1);
    glds16(wtu + bof0 + k0, ldsBu0);
    glds16(wtu + bof1 + k0, ldsBu1);
    __syncthreads();

    bf16x8_t a[4];
    #pragma unroll
    for (int rg = 0; rg < 4; ++rg)
      a[rg] = *(const bf16x8_t*)(&sA[(wr * 64 + rg * 16 + l16) * 32 + quad * 8]);
    #pragma unroll
    for (int cg = 0; cg < 4; ++cg) {
      bf16x8_t bg = *(const bf16x8_t*)(&sBg[(wc * 64 + cg * 16 + l16) * 32 + quad * 8]);
      bf16x8_t bu = *(const bf16x8_t*)(&sBu[(wc * 64 + cg * 16 + l16) * 32 + quad * 8]);
      #pragma unroll
      for (int rg = 0; rg < 4; ++rg) {
        accg[rg][cg] = __builtin_amdgcn_mfma_f32_16x16x32_bf16(a[rg], bg, accg[rg][cg], 0, 0, 0);
        accu[rg][cg] = __builtin_amdgcn_mfma_f32_16x16x32_bf16(a[rg], bu, accu[rg][cg], 0, 0, 0);
      }
    }
    __syncthreads();
  }

  #pragma unroll
  for (int rg = 0; rg < 4; ++rg) {
    #pragma unroll
    for (int r = 0; r < 4; ++r) {
      const int row = wr * 64 + rg * 16 + quad * 4 + r;
      if (row < tile_rows) {
        __bf16* orow = inter + (size_t)(r0 + row) * MDIM + n0 + wc * 64 + l16;
        #pragma unroll
        for (int cg = 0; cg < 4; ++cg) {
          const float gv = accg[rg][cg][r];
          const float uv = accu[rg][cg][r];
          orow[cg * 16] = (__bf16)(gv / (1.f + __expf(-gv)) * uv);
        }
      }
    }
  }
}

// ---------------- 4. gemm2: down proj + weighted atomic combine ----------------
__global__ __launch_bounds__(256) void gemm2_kernel(
    const __bf16* __restrict__ inter, const __bf16* __restrict__ wtd,
    const int* __restrict__ meta, const int* __restrict__ row_token,
    const float* __restrict__ row_w, float* __restrict__ out)
{
  const int e  = blockIdx.x >> 4;
  const int mt = blockIdx.x & 15;
  const int off0 = meta[64 + e], off1 = meta[64 + e + 1];
  const int rows = off1 - off0;
  if (mt * 128 >= rows) return;
  const int r0 = off0 + mt * 128;
  const int tile_rows = min(128, rows - mt * 128);
  const int n0 = blockIdx.y * 128;

  __shared__ __align__(16) __bf16 sA[128 * 32];
  __shared__ __align__(16) __bf16 sB[128 * 32];
  __shared__ int stok[128];
  __shared__ float swt[128];

  const int tid = threadIdx.x;
  if (tid < 128) {
    const int pos = min(r0 + tid, NPAIR - 1);
    stok[tid] = row_token[pos];
    swt[tid] = row_w[pos];
  }
  __syncthreads();

  const int wave = tid >> 6, lane = tid & 63;
  const int quad = lane >> 4, l16 = lane & 15;
  const int wr = wave >> 1, wc = wave & 1;

  const int slot0 = wave * 128 + lane;
  const int slot1 = slot0 + 64;
  const size_t aof0 = (size_t)min(r0 + (slot0 >> 2), NPAIR - 1) * MDIM + (slot0 & 3) * 8;
  const size_t aof1 = (size_t)min(r0 + (slot1 >> 2), NPAIR - 1) * MDIM + (slot1 & 3) * 8;
  const size_t bof0 = ((size_t)e * DIM + n0 + (slot0 >> 2)) * MDIM + (slot0 & 3) * 8;
  const size_t bof1 = ((size_t)e * DIM + n0 + (slot1 >> 2)) * MDIM + (slot1 & 3) * 8;
  __bf16* ldsA0 = &sA[(wave * 128) * 8];
  __bf16* ldsA1 = &sA[(wave * 128 + 64) * 8];
  __bf16* ldsB0 = &sB[(wave * 128) * 8];
  __bf16* ldsB1 = &sB[(wave * 128 + 64) * 8];

  f32x4_t acc[4][4];
  const f32x4_t z = {0.f, 0.f, 0.f, 0.f};
  #pragma unroll
  for (int i = 0; i < 4; ++i)
    #pragma unroll
    for (int j = 0; j < 4; ++j) acc[i][j] = z;

  for (int k0 = 0; k0 < MDIM; k0 += 32) {
    glds16(inter + aof0 + k0, ldsA0);
    glds16(inter + aof1 + k0, ldsA1);
    glds16(wtd   + bof0 + k0, ldsB0);
    glds16(wtd   + bof1 + k0, ldsB1);
    __syncthreads();

    bf16x8_t a[4];
    #pragma unroll
    for (int rg = 0; rg < 4; ++rg)
      a[rg] = *(const bf16x8_t*)(&sA[(wr * 64 + rg * 16 + l16) * 32 + quad * 8]);
    #pragma unroll
    for (int cg = 0; cg < 4; ++cg) {
      bf16x8_t b = *(const bf16x8_t*)(&sB[(wc * 64 + cg * 16 + l16) * 32 + quad * 8]);
      #pragma unroll
      for (int rg = 0; rg < 4; ++rg)
        acc[rg][cg] = __builtin_amdgcn_mfma_f32_16x16x32_bf16(a[rg], b, acc[rg][cg], 0, 0, 0);
    }
    __syncthreads();
  }

  #pragma unroll
  for (int rg = 0; rg < 4; ++rg) {
    #pragma unroll
    for (int r = 0; r < 4; ++r) {
      const int row = wr * 64 + rg * 16 + quad * 4 + r;
      if (row < tile_rows) {
        const int tok = stok[row];
        const float wt = swt[row];
        float* obase = out + (size_t)tok * DIM + n0 + wc * 64 + l16;
        #pragma unroll
        for (int cg = 0; cg < 4; ++cg)
          atomicAdd(obase + cg * 16, wt * acc[rg][cg][r]);
      }
    }
  }
}

extern "C" void kernel_launch(void* const* d_in, const int* in_sizes, int n_in,
                              void* d_out, int out_size, void* d_ws, size_t ws_size,
                              hipStream_t stream) {
  (void)in_sizes; (void)n_in; (void)ws_size;
  const float* x      = (const float*)d_in[0];  // [4,1024,2048]
  const float* gk     = (const float*)d_in[1];  // [2048,32]
  const float* gate_w = (const float*)d_in[2];  // [32,2048,768]
  const float* up_w   = (const float*)d_in[3];  // [32,2048,768]
  const float* down_w = (const float*)d_in[4];  // [32,768,2048]
  float* out = (float*)d_out;

  char* ws = (char*)d_ws;
  size_t o = 0;
  auto alloc = [&](size_t bytes) { size_t cur = o; o = (o + bytes + 255) & ~(size_t)255; return cur; };
  __bf16* xb        = (__bf16*)(ws + alloc((size_t)NTOK * DIM * 2));
  __bf16* inter     = (__bf16*)(ws + alloc((size_t)NPAIR * MDIM * 2));
  __bf16* wtg       = (__bf16*)(ws + alloc((size_t)NEXP * DIM * MDIM * 2));
  __bf16* wtu       = (__bf16*)(ws + alloc((size_t)NEXP * DIM * MDIM * 2));
  __bf16* wtd       = (__bf16*)(ws + alloc((size_t)NEXP * DIM * MDIM * 2));
  int*    row_token = (int*)   (ws + alloc((size_t)NPAIR * 4));
  float*  row_w     = (float*) (ws + alloc((size_t)NPAIR * 4));
  float*  topk_w    = (float*) (ws + alloc((size_t)NPAIR * 4));
  int*    topk_e    = (int*)   (ws + alloc((size_t)NPAIR * 4));
  int*    meta      = (int*)   (ws + alloc(512));

  hipMemsetAsync(d_out, 0, (size_t)out_size * sizeof(float), stream);

  // weight transposes: fp32 [E][K][N] -> bf16 [E][N][K]
  wtrans_kernel<<<dim3((DIM / 128) * (MDIM / 32), NEXP), 256, 0, stream>>>(gate_w, wtg, DIM, MDIM, MDIM / 32);
  wtrans_kernel<<<dim3((DIM / 128) * (MDIM / 32), NEXP), 256, 0, stream>>>(up_w,   wtu, DIM, MDIM, MDIM / 32);
  wtrans_kernel<<<dim3((MDIM / 128) * (DIM / 32), NEXP), 256, 0, stream>>>(down_w, wtd, MDIM, DIM, DIM / 32);

  router_kernel<<<NTOK, 256, 0, stream>>>(x, gk, xb, topk_w, topk_e);
  scatter_kernel<<<1, 1024, 0, stream>>>(topk_e, topk_w, meta, row_token, row_w);
  gemm1_kernel<<<dim3(NEXP * 16, MDIM / 128), 256, 0, stream>>>(xb, wtg, wtu, meta, row_token, inter);
  gemm2_kernel<<<dim3(NEXP * 16, DIM / 128), 256, 0, stream>>>(inter, wtd, meta, row_token, row_w, out);
}